// Round 1
// baseline (1468.375 us; speedup 1.0000x reference)
//
#include <hip/hip_runtime.h>

// Problem constants (fixed instance)
#define T_TOK 2048
#define K_DIM 2048
#define I_DIM 1024
#define NE    8
#define TOPK  2
#define GS    64

#define NSLOT  (T_TOK * TOPK)      // 4096 routed slots
#define TOTROW (NSLOT + T_TOK)     // + shared-expert rows = 6144
#define MAXTILE 32                 // worst case 4096/128 tiles per expert

#define BM  128                    // token rows per block
#define BK  32                     // k-slice per stage (== half a scale group)
#define BNG 64                     // gate cols per block (same count of up cols)
#define DBN 128                    // down-GEMM output cols per block

// ---- workspace layout (bytes) ----
// 0      : int gcnt[16]
// 64     : int gbase[16]
// 128    : int tok[TOTROW]
// +      : float prob[TOTROW]
// 65536  : float act[TOTROW][I_DIM]   (~25.2 MB total ws)

__device__ __forceinline__ float fp4_val(unsigned nib, float s) {
    // E2M1: {0,.5,1,1.5,2,3,4,6} with sign bit 3
    unsigned m = nib & 7u;
    unsigned bits = ((126u + (m >> 1)) << 23) | ((m & 1u) << 22); // valid for m>=2
    float v = (m >= 2u) ? __uint_as_float(bits) : (m == 1u ? 0.5f : 0.0f);
    v = __uint_as_float(__float_as_uint(v) ^ ((nib & 8u) << 28)); // sign
    return v * s;
}

__global__ void k_route(const int* __restrict__ eids, const float* __restrict__ probs,
                        int* __restrict__ gcnt, int* __restrict__ gbase,
                        int* __restrict__ tok, float* __restrict__ prob) {
    __shared__ int lcnt[NE], lbase[NE], lcur[NE];
    int tid = threadIdx.x;
    if (tid < NE) lcnt[tid] = 0;
    __syncthreads();
    for (int i = tid; i < NSLOT; i += blockDim.x)
        atomicAdd(&lcnt[eids[i]], 1);
    __syncthreads();
    if (tid == 0) {
        int acc = 0;
        for (int e = 0; e < NE; e++) { lbase[e] = acc; acc += lcnt[e]; }
    }
    __syncthreads();
    if (tid < NE) lcur[tid] = lbase[tid];
    __syncthreads();
    for (int i = tid; i < NSLOT; i += blockDim.x) {
        int e = eids[i];
        int pos = atomicAdd(&lcur[e], 1);
        tok[pos]  = i >> 1;       // token = slot / TOPK
        prob[pos] = probs[i];
    }
    for (int t = tid; t < T_TOK; t += blockDim.x) {  // shared expert = "expert 8"
        tok[NSLOT + t]  = t;
        prob[NSLOT + t] = 1.0f;   // SHARED_EXPERT_WEIGHT
    }
    if (tid < NE) { gcnt[tid] = lcnt[tid]; gbase[tid] = lbase[tid]; }
    if (tid == 0) { gcnt[NE] = T_TOK; gbase[NE] = NSLOT; }
}

// act[p, n] = silu(x@Wg)[p,n] * (x@Wu)[p,n], n in [0, I_DIM)
__global__ __launch_bounds__(256) void k_gateup(
        const float* __restrict__ x,
        const int* __restrict__ gup, const float* __restrict__ gus,
        const int* __restrict__ sup, const float* __restrict__ sus,
        const int* __restrict__ gcnt, const int* __restrict__ gbase,
        const int* __restrict__ tokid, float* __restrict__ act) {
    int e   = blockIdx.z;
    int cnt = gcnt[e];
    int m0  = blockIdx.y * BM;
    if (m0 >= cnt) return;
    int n0   = blockIdx.x * BNG;
    int base = gbase[e];
    const int*   wp; const float* sp;
    if (e < NE) { wp = gup + (size_t)e * (K_DIM / 8) * (2 * I_DIM);
                  sp = gus + (size_t)e * (K_DIM / GS) * (2 * I_DIM); }
    else        { wp = sup; sp = sus; }

    __shared__ float xs[BK][BM + 4];     // transposed x tile: [k][row]
    __shared__ float wg[BK][BNG + 4];
    __shared__ float wu[BK][BNG + 4];
    __shared__ int   ltok[BM];

    int tid = threadIdx.x;
    int tx = tid & 15, ty = tid >> 4;

    if (tid < BM) ltok[tid] = (m0 + tid < cnt) ? tokid[base + m0 + tid] : 0;

    float accg[8][4] = {}; float accu[8][4] = {};

    for (int k0 = 0; k0 < K_DIM; k0 += BK) {
        __syncthreads();
        // stage x: 128 rows x 32 k, transposed into LDS
        #pragma unroll
        for (int it = 0; it < 4; it++) {
            int idx = it * 256 + tid;
            int row = idx >> 3, cq = idx & 7;
            float4 v = make_float4(0.f, 0.f, 0.f, 0.f);
            if (m0 + row < cnt)
                v = *(const float4*)(x + (size_t)ltok[row] * K_DIM + k0 + cq * 4);
            xs[cq * 4 + 0][row] = v.x; xs[cq * 4 + 1][row] = v.y;
            xs[cq * 4 + 2][row] = v.z; xs[cq * 4 + 3][row] = v.w;
        }
        // stage + dequant weights: 256 gate words + 256 up words
        int kp0   = k0 >> 3;
        int sgrow = (k0 >> 6) * (2 * I_DIM);
        #pragma unroll
        for (int it = 0; it < 2; it++) {
            int idx = it * 256 + tid;
            int which = idx >> 8, rem = idx & 255;
            int pr = rem >> 6, c = rem & 63;
            int col = (which ? I_DIM + n0 : n0) + c;
            unsigned w = (unsigned)wp[(size_t)(kp0 + pr) * (2 * I_DIM) + col];
            float s = sp[sgrow + col];
            float (*dw)[BNG + 4] = which ? wu : wg;
            #pragma unroll
            for (int j = 0; j < 8; j++)
                dw[pr * 8 + j][c] = fp4_val((w >> (4 * j)) & 0xFu, s);
        }
        __syncthreads();
        #pragma unroll 8
        for (int kk = 0; kk < BK; kk++) {
            float a[8], bg[4], bu[4];
            *(float4*)&a[0]  = *(const float4*)&xs[kk][ty * 8];
            *(float4*)&a[4]  = *(const float4*)&xs[kk][ty * 8 + 4];
            *(float4*)&bg[0] = *(const float4*)&wg[kk][tx * 4];
            *(float4*)&bu[0] = *(const float4*)&wu[kk][tx * 4];
            #pragma unroll
            for (int i = 0; i < 8; i++)
                #pragma unroll
                for (int j = 0; j < 4; j++) {
                    accg[i][j] += a[i] * bg[j];
                    accu[i][j] += a[i] * bu[j];
                }
        }
    }
    #pragma unroll
    for (int i = 0; i < 8; i++) {
        int row = ty * 8 + i;
        if (m0 + row < cnt) {
            size_t p = (size_t)(base + m0 + row);
            float4 o;
            float g, u;
            g = accg[i][0]; u = accu[i][0]; o.x = g / (1.f + __expf(-g)) * u;
            g = accg[i][1]; u = accu[i][1]; o.y = g / (1.f + __expf(-g)) * u;
            g = accg[i][2]; u = accu[i][2]; o.z = g / (1.f + __expf(-g)) * u;
            g = accg[i][3]; u = accu[i][3]; o.w = g / (1.f + __expf(-g)) * u;
            *(float4*)(act + p * I_DIM + n0 + tx * 4) = o;
        }
    }
}

// out[tok, n] += prob * (act @ Wd)[p, n]
__global__ __launch_bounds__(256) void k_down(
        const float* __restrict__ act,
        const int* __restrict__ dwp, const float* __restrict__ dsc,
        const int* __restrict__ sdp, const float* __restrict__ sds,
        const int* __restrict__ gcnt, const int* __restrict__ gbase,
        const int* __restrict__ tokid, const float* __restrict__ sprob,
        float* __restrict__ out) {
    int e   = blockIdx.z;
    int cnt = gcnt[e];
    int m0  = blockIdx.y * BM;
    if (m0 >= cnt) return;
    int n0   = blockIdx.x * DBN;
    int base = gbase[e];
    const int* wp; const float* sp;
    if (e < NE) { wp = dwp + (size_t)e * (I_DIM / 8) * K_DIM;
                  sp = dsc + (size_t)e * (I_DIM / GS) * K_DIM; }
    else        { wp = sdp; sp = sds; }

    __shared__ float xs[BK][BM + 4];
    __shared__ float wt[BK][DBN + 4];
    __shared__ int   ltok[BM];
    __shared__ float lprob[BM];

    int tid = threadIdx.x;
    int tx = tid & 15, ty = tid >> 4;

    if (tid < BM) {
        bool v = (m0 + tid < cnt);
        ltok[tid]  = v ? tokid[base + m0 + tid] : 0;
        lprob[tid] = v ? sprob[base + m0 + tid] : 0.f;
    }

    float acc[8][8] = {};

    for (int i0 = 0; i0 < I_DIM; i0 += BK) {
        __syncthreads();
        #pragma unroll
        for (int it = 0; it < 4; it++) {
            int idx = it * 256 + tid;
            int row = idx >> 3, cq = idx & 7;
            float4 v = make_float4(0.f, 0.f, 0.f, 0.f);
            if (m0 + row < cnt)
                v = *(const float4*)(act + (size_t)(base + m0 + row) * I_DIM + i0 + cq * 4);
            xs[cq * 4 + 0][row] = v.x; xs[cq * 4 + 1][row] = v.y;
            xs[cq * 4 + 2][row] = v.z; xs[cq * 4 + 3][row] = v.w;
        }
        int kp0  = i0 >> 3;
        int srow = (i0 >> 6) * K_DIM;
        #pragma unroll
        for (int it = 0; it < 2; it++) {
            int idx = it * 256 + tid;
            int pr = idx >> 7, c = idx & 127;
            unsigned w = (unsigned)wp[(size_t)(kp0 + pr) * K_DIM + n0 + c];
            float s = sp[srow + n0 + c];
            #pragma unroll
            for (int j = 0; j < 8; j++)
                wt[pr * 8 + j][c] = fp4_val((w >> (4 * j)) & 0xFu, s);
        }
        __syncthreads();
        #pragma unroll 4
        for (int kk = 0; kk < BK; kk++) {
            float a[8], b[8];
            *(float4*)&a[0] = *(const float4*)&xs[kk][ty * 8];
            *(float4*)&a[4] = *(const float4*)&xs[kk][ty * 8 + 4];
            *(float4*)&b[0] = *(const float4*)&wt[kk][tx * 8];
            *(float4*)&b[4] = *(const float4*)&wt[kk][tx * 8 + 4];
            #pragma unroll
            for (int i = 0; i < 8; i++)
                #pragma unroll
                for (int j = 0; j < 8; j++)
                    acc[i][j] += a[i] * b[j];
        }
    }
    #pragma unroll
    for (int i = 0; i < 8; i++) {
        int row = ty * 8 + i;
        if (m0 + row < cnt) {
            int t = ltok[row];
            float pr = lprob[row];
            float* orow = out + (size_t)t * K_DIM + n0 + tx * 8;
            #pragma unroll
            for (int j = 0; j < 8; j++)
                atomicAdd(&orow[j], pr * acc[i][j]);
        }
    }
}

extern "C" void kernel_launch(void* const* d_in, const int* in_sizes, int n_in,
                              void* d_out, int out_size, void* d_ws, size_t ws_size,
                              hipStream_t stream) {
    const float* x    = (const float*)d_in[0];
    const int*   gup  = (const int*)d_in[1];
    const float* gus  = (const float*)d_in[2];
    const int*   dwp  = (const int*)d_in[3];
    const float* dsc  = (const float*)d_in[4];
    const int*   sup  = (const int*)d_in[5];
    const float* sus  = (const float*)d_in[6];
    const int*   sdp  = (const int*)d_in[7];
    const float* sds  = (const float*)d_in[8];
    const int*   eids = (const int*)d_in[9];
    const float* prb  = (const float*)d_in[10];
    float* out = (float*)d_out;

    char*  ws    = (char*)d_ws;
    int*   gcnt  = (int*)(ws + 0);
    int*   gbase = (int*)(ws + 64);
    int*   tok   = (int*)(ws + 128);
    float* prob  = (float*)(ws + 128 + TOTROW * 4);
    float* act   = (float*)(ws + 65536);   // TOTROW * I_DIM floats

    hipMemsetAsync(d_out, 0, (size_t)out_size * sizeof(float), stream);
    k_route<<<1, 256, 0, stream>>>(eids, prb, gcnt, gbase, tok, prob);
    k_gateup<<<dim3(I_DIM / BNG, MAXTILE, NE + 1), 256, 0, stream>>>(
        x, gup, gus, sup, sus, gcnt, gbase, tok, act);
    k_down<<<dim3(K_DIM / DBN, MAXTILE, NE + 1), 256, 0, stream>>>(
        act, dwp, dsc, sdp, sds, gcnt, gbase, tok, prob, out);
}

// Round 2
// 372.532 us; speedup vs baseline: 3.9416x; 3.9416x over previous
//
#include <hip/hip_runtime.h>
#include <hip/hip_bf16.h>

// Problem constants (fixed instance)
#define T_TOK 2048
#define K_DIM 2048
#define I_DIM 1024
#define NE    8
#define TOPK  2
#define GS    64

#define NSLOT  (T_TOK * TOPK)      // 4096 routed slots
#define TOTROW (NSLOT + T_TOK)     // + shared-expert rows = 6144
#define MAXTILE 32

typedef __attribute__((ext_vector_type(8))) short short8;   // 8 bf16 (MFMA A/B frag)
typedef __attribute__((ext_vector_type(4))) float f32x4;    // MFMA C/D frag

// ---- workspace layout (bytes) ----
// 0        : int gcnt[16]
// 64       : int gbase[16]
// 128      : int tok[TOTROW]
// 24704    : float prob[TOTROW]
// 65536    : ushort xb[T][K]        bf16, sigma-permuted (8.39 MB)
// 8454144  : ushort act[TOTROW][I]  bf16, sigma-permuted (12.6 MB)
#define WS_XB  65536
#define WS_ACT 8454144

// k-permutation within each 8-block: slot j holds original k = sigma(j)
// sigma = {0,2,4,6,1,3,5,7}  (falls out of nibble byte-decode for free)

__device__ __forceinline__ unsigned pack2(float a, float b) {
    __hip_bfloat162 h = __float22bfloat162_rn(make_float2(a, b)); // x=low
    return *reinterpret_cast<unsigned*>(&h);
}

__device__ __forceinline__ unsigned scale2(unsigned p, float s) {
    // p = two unscaled bf16 (exact fp4 values); return two scaled bf16
    float f0 = __uint_as_float(p << 16) * s;
    float f1 = __uint_as_float(p & 0xFFFF0000u) * s;
    return pack2(f0, f1);
}

// Decode one packed word (8 fp4 along k) -> 4 u32 of scaled bf16 pairs,
// in sigma order: slots {0,2},{4,6},{1,3},{5,7}.
__device__ __forceinline__ void dq_word(unsigned w, float s, unsigned o[4]) {
    unsigned lo  = w & 0x0F0F0F0Fu;          // nibbles 0,2,4,6
    unsigned hi  = (w >> 4) & 0x0F0F0F0Fu;   // nibbles 1,3,5,7
    unsigned mlo = lo & 0x07070707u, mhi = hi & 0x07070707u;
    // bf16 high byte table[m] = {00,3F,3F,3F,40,40,40,40}; low byte {00,00,80,C0,00,40,80,C0}
    unsigned Hlo = __builtin_amdgcn_perm(0x40404040u, 0x3F3F3F00u, mlo);
    unsigned Hhi = __builtin_amdgcn_perm(0x40404040u, 0x3F3F3F00u, mhi);
    unsigned Llo = __builtin_amdgcn_perm(0xC0804000u, 0xC0800000u, mlo);
    unsigned Lhi = __builtin_amdgcn_perm(0xC0804000u, 0xC0800000u, mhi);
    Hlo |= (lo & 0x08080808u) << 4;          // sign -> bit7 of high byte
    Hhi |= (hi & 0x08080808u) << 4;
    unsigned e01 = __builtin_amdgcn_perm(Hlo, Llo, 0x05010400u); // bf16(v0),bf16(v2)
    unsigned e23 = __builtin_amdgcn_perm(Hlo, Llo, 0x07030602u); // v4,v6
    unsigned o01 = __builtin_amdgcn_perm(Hhi, Lhi, 0x05010400u); // v1,v3
    unsigned o23 = __builtin_amdgcn_perm(Hhi, Lhi, 0x07030602u); // v5,v7
    o[0] = scale2(e01, s); o[1] = scale2(e23, s);
    o[2] = scale2(o01, s); o[3] = scale2(o23, s);
}

__global__ void k_route(const int* __restrict__ eids, const float* __restrict__ probs,
                        int* __restrict__ gcnt, int* __restrict__ gbase,
                        int* __restrict__ tok, float* __restrict__ prob) {
    __shared__ int lcnt[NE], lbase[NE], lcur[NE];
    int tid = threadIdx.x;
    if (tid < NE) lcnt[tid] = 0;
    __syncthreads();
    for (int i = tid; i < NSLOT; i += blockDim.x)
        atomicAdd(&lcnt[eids[i]], 1);
    __syncthreads();
    if (tid == 0) {
        int acc = 0;
        for (int e = 0; e < NE; e++) { lbase[e] = acc; acc += lcnt[e]; }
    }
    __syncthreads();
    if (tid < NE) lcur[tid] = lbase[tid];
    __syncthreads();
    for (int i = tid; i < NSLOT; i += blockDim.x) {
        int e = eids[i];
        int pos = atomicAdd(&lcur[e], 1);
        tok[pos]  = i >> 1;
        prob[pos] = probs[i];
    }
    for (int t = tid; t < T_TOK; t += blockDim.x) {
        tok[NSLOT + t]  = t;
        prob[NSLOT + t] = 1.0f;
    }
    if (tid < NE) { gcnt[tid] = lcnt[tid]; gbase[tid] = lbase[tid]; }
    if (tid == 0) { gcnt[NE] = T_TOK; gbase[NE] = NSLOT; }
}

// x fp32 -> bf16 with sigma permutation applied per 8-block
__global__ __launch_bounds__(256) void k_prep(const float* __restrict__ x,
                                              ushort* __restrict__ xb) {
    int idx = blockIdx.x * 256 + threadIdx.x;     // one 8-float chunk each
    const float4* p = (const float4*)(x + (size_t)idx * 8);
    float4 f0 = p[0], f1 = p[1];
    unsigned u0 = pack2(f0.x, f0.z);  // slots 0,1 <- k 0,2
    unsigned u1 = pack2(f1.x, f1.z);  // slots 2,3 <- k 4,6
    unsigned u2 = pack2(f0.y, f0.w);  // slots 4,5 <- k 1,3
    unsigned u3 = pack2(f1.y, f1.w);  // slots 6,7 <- k 5,7
    *(int4*)(xb + (size_t)idx * 8) = make_int4(u0, u1, u2, u3);
}

// act[p, n] = silu(x@Wg) * (x@Wu), MFMA 128x128 tile (gate 64 | up 64)
__global__ __launch_bounds__(256) void k_gemm_gateup(
        const ushort* __restrict__ xb,
        const int* __restrict__ gup, const float* __restrict__ gus,
        const int* __restrict__ sup, const float* __restrict__ sus,
        const int* __restrict__ gcnt, const int* __restrict__ gbase,
        const int* __restrict__ tokid, ushort* __restrict__ act) {
    int e = blockIdx.z, cnt = gcnt[e], m0 = blockIdx.y * 128;
    if (m0 >= cnt) return;
    int n0 = blockIdx.x * 64;
    int base = gbase[e];
    const int* wp; const float* sp;
    if (e < NE) { wp = gup + (size_t)e * (K_DIM / 8) * 2048;
                  sp = gus + (size_t)e * (K_DIM / GS) * 2048; }
    else        { wp = sup; sp = sus; }

    __shared__ __align__(16) ushort xs[128][72];
    __shared__ __align__(16) ushort wb[128][72];
    __shared__ int ltok[128];

    int tid = threadIdx.x;
    int lane = tid & 63, wv = tid >> 6, lid = lane & 15, quad = lane >> 4;
    int wm = wv * 32;
    int c = tid & 127, wq = tid >> 7;
    int gcol = (c < 64) ? (n0 + c) : (I_DIM + n0 + (c - 64));

    if (tid < 128) ltok[tid] = (m0 + tid < cnt) ? tokid[base + m0 + tid] : 0;

    f32x4 acc[2][8] = {};

    for (int k0 = 0; k0 < K_DIM; k0 += 64) {
        __syncthreads();
        #pragma unroll
        for (int it = 0; it < 4; it++) {           // x tile: 128 rows x 64 k
            int idx = it * 256 + tid;
            int row = idx >> 3, q = idx & 7;
            int4 v = make_int4(0, 0, 0, 0);
            if (m0 + row < cnt)
                v = *(const int4*)(xb + (size_t)ltok[row] * K_DIM + k0 + q * 8);
            *(int4*)&xs[row][q * 8] = v;
        }
        {                                           // weights: 128 cols x 8 words
            int kp0 = k0 >> 3;
            float s = sp[(k0 >> 6) * 2048 + gcol];
            #pragma unroll
            for (int i = 0; i < 4; i++) {
                int w8 = wq * 4 + i;
                unsigned wd = (unsigned)wp[(size_t)(kp0 + w8) * 2048 + gcol];
                unsigned o[4]; dq_word(wd, s, o);
                *(int4*)&wb[c][w8 * 8] = make_int4(o[0], o[1], o[2], o[3]);
            }
        }
        __syncthreads();
        #pragma unroll
        for (int ks = 0; ks < 2; ks++) {
            int kslot = ks * 32 + quad * 8;
            short8 a0 = *(const short8*)&xs[wm + lid][kslot];
            short8 a1 = *(const short8*)&xs[wm + 16 + lid][kslot];
            #pragma unroll
            for (int nt = 0; nt < 8; nt++) {
                short8 b = *(const short8*)&wb[nt * 16 + lid][kslot];
                acc[0][nt] = __builtin_amdgcn_mfma_f32_16x16x32_bf16(a0, b, acc[0][nt], 0, 0, 0);
                acc[1][nt] = __builtin_amdgcn_mfma_f32_16x16x32_bf16(a1, b, acc[1][nt], 0, 0, 0);
            }
        }
    }
    // epilogue: silu(gate)*up, store bf16 with sigma applied on I-dim
    int c7 = lid & 7;
    int delta = ((c7 >> 1) + ((c7 & 1) << 2)) - c7;   // sigma^-1 remap
    #pragma unroll
    for (int mt = 0; mt < 2; mt++) {
        #pragma unroll
        for (int r = 0; r < 4; r++) {
            int row = wm + mt * 16 + quad * 4 + r;
            if (m0 + row < cnt) {
                size_t p = (size_t)(base + m0 + row);
                #pragma unroll
                for (int nt = 0; nt < 4; nt++) {
                    float g = acc[mt][nt][r], u = acc[mt][nt + 4][r];
                    float vv = g / (1.f + __expf(-g)) * u;
                    int n = n0 + nt * 16 + lid;
                    __hip_bfloat16 hb = __float2bfloat16(vv);
                    act[p * I_DIM + n + delta] = *reinterpret_cast<ushort*>(&hb);
                }
            }
        }
    }
}

// out[tok, n] += prob * (act @ Wd), MFMA 128x128 tile
__global__ __launch_bounds__(256) void k_gemm_down(
        const ushort* __restrict__ actb,
        const int* __restrict__ dwp, const float* __restrict__ dsc,
        const int* __restrict__ sdp, const float* __restrict__ sds,
        const int* __restrict__ gcnt, const int* __restrict__ gbase,
        const int* __restrict__ tokid, const float* __restrict__ sprob,
        float* __restrict__ out) {
    int e = blockIdx.z, cnt = gcnt[e], m0 = blockIdx.y * 128;
    if (m0 >= cnt) return;
    int n0 = blockIdx.x * 128;
    int base = gbase[e];
    const int* wp; const float* sp;
    if (e < NE) { wp = dwp + (size_t)e * (I_DIM / 8) * 2048;
                  sp = dsc + (size_t)e * (I_DIM / GS) * 2048; }
    else        { wp = sdp; sp = sds; }

    __shared__ __align__(16) ushort xs[128][72];
    __shared__ __align__(16) ushort wb[128][72];
    __shared__ int ltok[128];
    __shared__ float lpr[128];

    int tid = threadIdx.x;
    int lane = tid & 63, wvv = tid >> 6, lid = lane & 15, quad = lane >> 4;
    int wm = wvv * 32;
    int c = tid & 127, wq = tid >> 7;
    int gcol = n0 + c;

    if (tid < 128) {
        bool v = (m0 + tid < cnt);
        ltok[tid] = v ? tokid[base + m0 + tid] : 0;
        lpr[tid]  = v ? sprob[base + m0 + tid] : 0.f;
    }

    f32x4 acc[2][8] = {};

    for (int i0 = 0; i0 < I_DIM; i0 += 64) {
        __syncthreads();
        #pragma unroll
        for (int it = 0; it < 4; it++) {
            int idx = it * 256 + tid;
            int row = idx >> 3, q = idx & 7;
            int4 v = make_int4(0, 0, 0, 0);
            if (m0 + row < cnt)
                v = *(const int4*)(actb + (size_t)(base + m0 + row) * I_DIM + i0 + q * 8);
            *(int4*)&xs[row][q * 8] = v;
        }
        {
            int kp0 = i0 >> 3;
            float s = sp[(i0 >> 6) * 2048 + gcol];
            #pragma unroll
            for (int i = 0; i < 4; i++) {
                int w8 = wq * 4 + i;
                unsigned wd = (unsigned)wp[(size_t)(kp0 + w8) * 2048 + gcol];
                unsigned o[4]; dq_word(wd, s, o);
                *(int4*)&wb[c][w8 * 8] = make_int4(o[0], o[1], o[2], o[3]);
            }
        }
        __syncthreads();
        #pragma unroll
        for (int ks = 0; ks < 2; ks++) {
            int kslot = ks * 32 + quad * 8;
            short8 a0 = *(const short8*)&xs[wm + lid][kslot];
            short8 a1 = *(const short8*)&xs[wm + 16 + lid][kslot];
            #pragma unroll
            for (int nt = 0; nt < 8; nt++) {
                short8 b = *(const short8*)&wb[nt * 16 + lid][kslot];
                acc[0][nt] = __builtin_amdgcn_mfma_f32_16x16x32_bf16(a0, b, acc[0][nt], 0, 0, 0);
                acc[1][nt] = __builtin_amdgcn_mfma_f32_16x16x32_bf16(a1, b, acc[1][nt], 0, 0, 0);
            }
        }
    }
    #pragma unroll
    for (int mt = 0; mt < 2; mt++) {
        #pragma unroll
        for (int r = 0; r < 4; r++) {
            int row = wm + mt * 16 + quad * 4 + r;
            if (m0 + row < cnt) {
                int t = ltok[row];
                float pr = lpr[row];
                float* orow = out + (size_t)t * K_DIM + n0 + lid;
                #pragma unroll
                for (int nt = 0; nt < 8; nt++)
                    atomicAdd(&orow[nt * 16], pr * acc[mt][nt][r]);
            }
        }
    }
}

extern "C" void kernel_launch(void* const* d_in, const int* in_sizes, int n_in,
                              void* d_out, int out_size, void* d_ws, size_t ws_size,
                              hipStream_t stream) {
    const float* x    = (const float*)d_in[0];
    const int*   gup  = (const int*)d_in[1];
    const float* gus  = (const float*)d_in[2];
    const int*   dwp  = (const int*)d_in[3];
    const float* dsc  = (const float*)d_in[4];
    const int*   sup  = (const int*)d_in[5];
    const float* sus  = (const float*)d_in[6];
    const int*   sdp  = (const int*)d_in[7];
    const float* sds  = (const float*)d_in[8];
    const int*   eids = (const int*)d_in[9];
    const float* prb  = (const float*)d_in[10];
    float* out = (float*)d_out;

    char*   ws    = (char*)d_ws;
    int*    gcnt  = (int*)(ws + 0);
    int*    gbase = (int*)(ws + 64);
    int*    tok   = (int*)(ws + 128);
    float*  prob  = (float*)(ws + 24704);
    ushort* xb    = (ushort*)(ws + WS_XB);
    ushort* act   = (ushort*)(ws + WS_ACT);

    hipMemsetAsync(d_out, 0, (size_t)out_size * sizeof(float), stream);
    k_route<<<1, 256, 0, stream>>>(eids, prb, gcnt, gbase, tok, prob);
    k_prep<<<(T_TOK * K_DIM / 8) / 256, 256, 0, stream>>>(x, xb);
    k_gemm_gateup<<<dim3(I_DIM / 64, MAXTILE, NE + 1), 256, 0, stream>>>(
        xb, gup, gus, sup, sus, gcnt, gbase, tok, act);
    k_gemm_down<<<dim3(K_DIM / 128, MAXTILE, NE + 1), 256, 0, stream>>>(
        act, dwp, dsc, sdp, sds, gcnt, gbase, tok, prob, out);
}

// Round 3
// 287.284 us; speedup vs baseline: 5.1112x; 1.2967x over previous
//
#include <hip/hip_runtime.h>
#include <hip/hip_bf16.h>

// Problem constants (fixed instance)
#define T_TOK 2048
#define K_DIM 2048
#define I_DIM 1024
#define NE    8
#define TOPK  2
#define GS    64

#define NSLOT  (T_TOK * TOPK)      // 4096 routed slots
#define TOTROW (NSLOT + T_TOK)     // + shared-expert rows = 6144
#define MAXTILE 32

typedef __attribute__((ext_vector_type(8))) short short8;   // 8 bf16 (MFMA A/B frag)
typedef __attribute__((ext_vector_type(4))) float f32x4;    // MFMA C/D frag

// ---- workspace layout (bytes) ----
#define WS_XB   ((size_t)65536)                       // ushort xb[2048][2048]
#define WS_ACT  (WS_XB  + (size_t)T_TOK * K_DIM * 2)  // ushort act[TOTROW][1024]
#define WS_WGU  (WS_ACT + (size_t)TOTROW * I_DIM * 2) // ushort wgu_t[9][2048][2048] (B^T, k sigma-permuted)
#define WS_WD   (WS_WGU + (size_t)9 * 2048 * 2048 * 2)// ushort wd_t[9][2048][1024]
// total ~134.3 MB

// sigma = {0,2,4,6,1,3,5,7} applied to k within each 8-block (both operands -> dot invariant)

__device__ __forceinline__ unsigned pack2(float a, float b) {
    __hip_bfloat162 h = __float22bfloat162_rn(make_float2(a, b)); // x=low
    return *reinterpret_cast<unsigned*>(&h);
}

__device__ __forceinline__ unsigned scale2(unsigned p, float s) {
    float f0 = __uint_as_float(p << 16) * s;
    float f1 = __uint_as_float(p & 0xFFFF0000u) * s;
    return pack2(f0, f1);
}

// Decode one packed word (8 fp4 along k) -> 4 u32 of scaled bf16 pairs, sigma order.
__device__ __forceinline__ void dq_word(unsigned w, float s, unsigned o[4]) {
    unsigned lo  = w & 0x0F0F0F0Fu;
    unsigned hi  = (w >> 4) & 0x0F0F0F0Fu;
    unsigned mlo = lo & 0x07070707u, mhi = hi & 0x07070707u;
    unsigned Hlo = __builtin_amdgcn_perm(0x40404040u, 0x3F3F3F00u, mlo);
    unsigned Hhi = __builtin_amdgcn_perm(0x40404040u, 0x3F3F3F00u, mhi);
    unsigned Llo = __builtin_amdgcn_perm(0xC0804000u, 0xC0800000u, mlo);
    unsigned Lhi = __builtin_amdgcn_perm(0xC0804000u, 0xC0800000u, mhi);
    Hlo |= (lo & 0x08080808u) << 4;
    Hhi |= (hi & 0x08080808u) << 4;
    unsigned e01 = __builtin_amdgcn_perm(Hlo, Llo, 0x05010400u);
    unsigned e23 = __builtin_amdgcn_perm(Hlo, Llo, 0x07030602u);
    unsigned o01 = __builtin_amdgcn_perm(Hhi, Lhi, 0x05010400u);
    unsigned o23 = __builtin_amdgcn_perm(Hhi, Lhi, 0x07030602u);
    o[0] = scale2(e01, s); o[1] = scale2(e23, s);
    o[2] = scale2(o01, s); o[3] = scale2(o23, s);
}

__device__ __forceinline__ void gld16(const void* g, void* l) {
    __builtin_amdgcn_global_load_lds(
        (const __attribute__((address_space(1))) unsigned*)g,
        (__attribute__((address_space(3))) unsigned*)l, 16, 0, 0);
}

__global__ void k_route(const int* __restrict__ eids, const float* __restrict__ probs,
                        int* __restrict__ gcnt, int* __restrict__ gbase,
                        int* __restrict__ tok, float* __restrict__ prob) {
    __shared__ int lcnt[NE], lbase[NE], lcur[NE];
    int tid = threadIdx.x;
    if (tid < NE) lcnt[tid] = 0;
    __syncthreads();
    for (int i = tid; i < NSLOT; i += blockDim.x)
        atomicAdd(&lcnt[eids[i]], 1);
    __syncthreads();
    if (tid == 0) {
        int acc = 0;
        for (int e = 0; e < NE; e++) { lbase[e] = acc; acc += lcnt[e]; }
    }
    __syncthreads();
    if (tid < NE) lcur[tid] = lbase[tid];
    __syncthreads();
    for (int i = tid; i < NSLOT; i += blockDim.x) {
        int e = eids[i];
        int pos = atomicAdd(&lcur[e], 1);
        tok[pos]  = i >> 1;
        prob[pos] = probs[i];
    }
    for (int t = tid; t < T_TOK; t += blockDim.x) {
        tok[NSLOT + t]  = t;
        prob[NSLOT + t] = 1.0f;
    }
    if (tid < NE) { gcnt[tid] = lcnt[tid]; gbase[tid] = lbase[tid]; }
    if (tid == 0) { gcnt[NE] = T_TOK; gbase[NE] = NSLOT; }
}

// x fp32 -> bf16 with sigma permutation per 8-block along K
__global__ __launch_bounds__(256) void k_prep(const float* __restrict__ x,
                                              ushort* __restrict__ xb) {
    int idx = blockIdx.x * 256 + threadIdx.x;
    const float4* p = (const float4*)(x + (size_t)idx * 8);
    float4 f0 = p[0], f1 = p[1];
    unsigned u0 = pack2(f0.x, f0.z);
    unsigned u1 = pack2(f1.x, f1.z);
    unsigned u2 = pack2(f0.y, f0.w);
    unsigned u3 = pack2(f1.y, f1.w);
    *(int4*)(xb + (size_t)idx * 8) = make_int4(u0, u1, u2, u3);
}

// Dequant fp4 -> bf16 B^T: out[e][n][k] (k sigma-permuted per 8)
// input packed [KW][N] per expert, scales [KW/8][N]. block (8,32): x=kw-in-tile, y=n-in-tile
__global__ __launch_bounds__(256) void k_dq(
        const int* __restrict__ wp_r, const float* __restrict__ sc_r,
        const int* __restrict__ wp_s, const float* __restrict__ sc_s,
        ushort* __restrict__ outp, int KW, int N) {
    int e = blockIdx.z;
    const int* wp; const float* sc;
    if (e < NE) { wp = wp_r + (size_t)e * KW * N; sc = sc_r + (size_t)e * (KW / 8) * N; }
    else        { wp = wp_s; sc = sc_s; }
    ushort* op = outp + (size_t)e * KW * 8 * N;
    int kwt = blockIdx.x * 8 + threadIdx.x;
    int n   = blockIdx.y * 32 + threadIdx.y;
    unsigned w = (unsigned)wp[(size_t)kwt * N + n];
    float s = sc[(size_t)(kwt >> 3) * N + n];
    unsigned o[4]; dq_word(w, s, o);
    *(int4*)(op + (size_t)n * (KW * 8) + kwt * 8) = make_int4(o[0], o[1], o[2], o[3]);
}

// ---- GEMM 1: act[p,n] = silu(x@Wg)*(x@Wu). 128 rows x 64 outcols (gate+up) per block.
__global__ __launch_bounds__(256) void k_gemm_gateup(
        const ushort* __restrict__ xb, const ushort* __restrict__ wgu_t,
        const int* __restrict__ gcnt, const int* __restrict__ gbase,
        const int* __restrict__ tokid, ushort* __restrict__ act) {
    int e = blockIdx.z, cnt = gcnt[e], m0 = blockIdx.y * 128;
    if (m0 >= cnt) return;
    int n0 = blockIdx.x * 64;
    int base = gbase[e];
    const ushort* wt = wgu_t + (size_t)e * 2048 * K_DIM;

    __shared__ __align__(16) ushort xs[128 * 64];
    __shared__ __align__(16) ushort bs[128 * 64];
    __shared__ int ltok[128];

    int tid = threadIdx.x;
    int lane = tid & 63, wv = tid >> 6;
    int lid = lane & 15, quad = lane >> 4;
    int wr = wv >> 1, wc = wv & 1;          // 2x2 waves, each 64 rows x 64 B-rows
    int l8 = lane >> 3, l7 = lane & 7;
    int chunk = (l7 ^ l8) * 8;              // XOR-swizzled source k-chunk (ushorts)

    if (tid < 128) ltok[tid] = (m0 + tid < cnt) ? tokid[base + m0 + tid] : 0;
    __syncthreads();

    const ushort* aSrc[4]; const ushort* bSrc[4];
    #pragma unroll
    for (int it = 0; it < 4; it++) {
        int rA = wv * 32 + it * 8 + l8;                 // rA & 7 == l8
        aSrc[it] = xb + (size_t)ltok[rA] * K_DIM + chunk;
        int h = rA >> 6, j = rA & 63;                    // B row -> weight col
        int col = (j < 32) ? (n0 + h * 32 + j) : (I_DIM + n0 + h * 32 + (j - 32));
        bSrc[it] = wt + (size_t)col * K_DIM + chunk;
    }

    f32x4 acc[4][4] = {};

    for (int k0 = 0; k0 < K_DIM; k0 += 64) {
        #pragma unroll
        for (int it = 0; it < 4; it++) {
            gld16(aSrc[it] + k0, &xs[(wv * 4 + it) * 512]);
            gld16(bSrc[it] + k0, &bs[(wv * 4 + it) * 512]);
        }
        __syncthreads();
        #pragma unroll
        for (int ks = 0; ks < 2; ks++) {
            int slot = ((ks * 4 + quad) ^ l7) * 8;
            short8 a[4], b[4];
            #pragma unroll
            for (int mt = 0; mt < 4; mt++)
                a[mt] = *(const short8*)&xs[(wr * 64 + mt * 16 + lid) * 64 + slot];
            #pragma unroll
            for (int nt = 0; nt < 4; nt++)
                b[nt] = *(const short8*)&bs[(wc * 64 + nt * 16 + lid) * 64 + slot];
            #pragma unroll
            for (int mt = 0; mt < 4; mt++)
                #pragma unroll
                for (int nt = 0; nt < 4; nt++)
                    acc[mt][nt] = __builtin_amdgcn_mfma_f32_16x16x32_bf16(
                        a[mt], b[nt], acc[mt][nt], 0, 0, 0);
        }
        __syncthreads();
    }

    int c7 = lid & 7;
    int delta = ((c7 >> 1) + ((c7 & 1) << 2)) - c7;   // sigma^-1 on stored I index
    #pragma unroll
    for (int mt = 0; mt < 4; mt++) {
        #pragma unroll
        for (int i = 0; i < 4; i++) {
            int row = wr * 64 + mt * 16 + quad * 4 + i;
            if (m0 + row < cnt) {
                size_t p = (size_t)(base + m0 + row);
                #pragma unroll
                for (int nt = 0; nt < 2; nt++) {
                    float g = acc[mt][nt][i], u = acc[mt][nt + 2][i];
                    float vv = g / (1.f + __expf(-g)) * u;
                    int ncol = n0 + wc * 32 + nt * 16 + lid;
                    __hip_bfloat16 hb = __float2bfloat16(vv);
                    act[p * I_DIM + ncol + delta] = *reinterpret_cast<ushort*>(&hb);
                }
            }
        }
    }
}

// ---- GEMM 2: out[tok,n] += prob * (act @ Wd). 128 rows x 128 cols per block.
__global__ __launch_bounds__(256) void k_gemm_down(
        const ushort* __restrict__ actb, const ushort* __restrict__ wd_t,
        const int* __restrict__ gcnt, const int* __restrict__ gbase,
        const int* __restrict__ tokid, const float* __restrict__ sprob,
        float* __restrict__ out) {
    int e = blockIdx.z, cnt = gcnt[e], m0 = blockIdx.y * 128;
    if (m0 >= cnt) return;
    int n0 = blockIdx.x * 128;
    int base = gbase[e];
    const ushort* wt = wd_t + (size_t)e * 2048 * I_DIM;

    __shared__ __align__(16) ushort xs[128 * 64];
    __shared__ __align__(16) ushort bs[128 * 64];
    __shared__ int   ltok[128];
    __shared__ float lpr[128];

    int tid = threadIdx.x;
    int lane = tid & 63, wv = tid >> 6;
    int lid = lane & 15, quad = lane >> 4;
    int wr = wv >> 1, wc = wv & 1;
    int l8 = lane >> 3, l7 = lane & 7;
    int chunk = (l7 ^ l8) * 8;

    if (tid < 128) {
        bool v = (m0 + tid < cnt);
        ltok[tid] = v ? tokid[base + m0 + tid] : 0;
        lpr[tid]  = v ? sprob[base + m0 + tid] : 0.f;
    }
    __syncthreads();

    const ushort* aSrc[4]; const ushort* bSrc[4];
    #pragma unroll
    for (int it = 0; it < 4; it++) {
        int rA = wv * 32 + it * 8 + l8;
        int rr = m0 + rA; if (rr >= cnt) rr = cnt - 1;
        aSrc[it] = actb + (size_t)(base + rr) * I_DIM + chunk;
        bSrc[it] = wt + (size_t)(n0 + rA) * I_DIM + chunk;
    }

    f32x4 acc[4][4] = {};

    for (int i0 = 0; i0 < I_DIM; i0 += 64) {
        #pragma unroll
        for (int it = 0; it < 4; it++) {
            gld16(aSrc[it] + i0, &xs[(wv * 4 + it) * 512]);
            gld16(bSrc[it] + i0, &bs[(wv * 4 + it) * 512]);
        }
        __syncthreads();
        #pragma unroll
        for (int ks = 0; ks < 2; ks++) {
            int slot = ((ks * 4 + quad) ^ l7) * 8;
            short8 a[4], b[4];
            #pragma unroll
            for (int mt = 0; mt < 4; mt++)
                a[mt] = *(const short8*)&xs[(wr * 64 + mt * 16 + lid) * 64 + slot];
            #pragma unroll
            for (int nt = 0; nt < 4; nt++)
                b[nt] = *(const short8*)&bs[(wc * 64 + nt * 16 + lid) * 64 + slot];
            #pragma unroll
            for (int mt = 0; mt < 4; mt++)
                #pragma unroll
                for (int nt = 0; nt < 4; nt++)
                    acc[mt][nt] = __builtin_amdgcn_mfma_f32_16x16x32_bf16(
                        a[mt], b[nt], acc[mt][nt], 0, 0, 0);
        }
        __syncthreads();
    }

    #pragma unroll
    for (int mt = 0; mt < 4; mt++) {
        #pragma unroll
        for (int i = 0; i < 4; i++) {
            int row = wr * 64 + mt * 16 + quad * 4 + i;
            if (m0 + row < cnt) {
                int t = ltok[row];
                float pr = lpr[row];
                float* orow = out + (size_t)t * K_DIM + n0 + wc * 64 + lid;
                #pragma unroll
                for (int nt = 0; nt < 4; nt++)
                    atomicAdd(&orow[nt * 16], pr * acc[mt][nt][i]);
            }
        }
    }
}

extern "C" void kernel_launch(void* const* d_in, const int* in_sizes, int n_in,
                              void* d_out, int out_size, void* d_ws, size_t ws_size,
                              hipStream_t stream) {
    const float* x    = (const float*)d_in[0];
    const int*   gup  = (const int*)d_in[1];
    const float* gus  = (const float*)d_in[2];
    const int*   dwp  = (const int*)d_in[3];
    const float* dsc  = (const float*)d_in[4];
    const int*   sup  = (const int*)d_in[5];
    const float* sus  = (const float*)d_in[6];
    const int*   sdp  = (const int*)d_in[7];
    const float* sds  = (const float*)d_in[8];
    const int*   eids = (const int*)d_in[9];
    const float* prb  = (const float*)d_in[10];
    float* out = (float*)d_out;

    char*   ws    = (char*)d_ws;
    int*    gcnt  = (int*)(ws + 0);
    int*    gbase = (int*)(ws + 64);
    int*    tok   = (int*)(ws + 128);
    float*  prob  = (float*)(ws + 24704);
    ushort* xb    = (ushort*)(ws + WS_XB);
    ushort* act   = (ushort*)(ws + WS_ACT);
    ushort* wgu_t = (ushort*)(ws + WS_WGU);
    ushort* wd_t  = (ushort*)(ws + WS_WD);

    hipMemsetAsync(d_out, 0, (size_t)out_size * sizeof(float), stream);
    k_route<<<1, 256, 0, stream>>>(eids, prb, gcnt, gbase, tok, prob);
    k_prep<<<(T_TOK * K_DIM / 8) / 256, 256, 0, stream>>>(x, xb);
    k_dq<<<dim3(32, 64, NE + 1), dim3(8, 32), 0, stream>>>(
        gup, gus, sup, sus, wgu_t, K_DIM / 8, 2 * I_DIM);
    k_dq<<<dim3(16, 64, NE + 1), dim3(8, 32), 0, stream>>>(
        dwp, dsc, sdp, sds, wd_t, I_DIM / 8, K_DIM);
    k_gemm_gateup<<<dim3(I_DIM / 64, MAXTILE, NE + 1), 256, 0, stream>>>(
        xb, wgu_t, gcnt, gbase, tok, act);
    k_gemm_down<<<dim3(K_DIM / 128, MAXTILE, NE + 1), 256, 0, stream>>>(
        act, wd_t, gcnt, gbase, tok, prob, out);
}

// Round 4
// 262.028 us; speedup vs baseline: 5.6039x; 1.0964x over previous
//
#include <hip/hip_runtime.h>
#include <hip/hip_bf16.h>

// Problem constants (fixed instance)
#define T_TOK 2048
#define K_DIM 2048
#define I_DIM 1024
#define NE    8
#define TOPK  2
#define GS    64

#define NSLOT  (T_TOK * TOPK)      // 4096 routed slots
#define TOTROW (NSLOT + T_TOK)     // + shared-expert rows = 6144
#define MAXTILE 32

typedef __attribute__((ext_vector_type(8))) short short8;   // 8 bf16 (MFMA A/B frag)
typedef __attribute__((ext_vector_type(4))) float f32x4;    // MFMA C/D frag

// ---- workspace layout (bytes) ----
// 0      gcnt[16] | 64 gbase[16] | 128 tok[6144] | 24704 inv[4096]
#define WS_XB   ((size_t)65536)                        // ushort xb[2048][2048]
#define WS_ACT  (WS_XB  + (size_t)2048 * 2048 * 2)     // ushort act[TOTROW][1024]
#define WS_Y    (WS_ACT + (size_t)TOTROW * 1024 * 2)   // ushort y[TOTROW][2048]
#define WS_WGU  (WS_Y   + (size_t)TOTROW * 2048 * 2)   // ushort wgu_t[9][2048][2048]
#define WS_WD   (WS_WGU + (size_t)9 * 2048 * 2048 * 2) // ushort wd_t[9][2048][1024]
// total ~159.5 MB

// sigma = {0,2,4,6,1,3,5,7} applied to k within each 8-block (both operands -> dot invariant)

__device__ __forceinline__ unsigned pack2(float a, float b) {
    __hip_bfloat162 h = __float22bfloat162_rn(make_float2(a, b)); // x=low
    return *reinterpret_cast<unsigned*>(&h);
}

__device__ __forceinline__ unsigned scale2(unsigned p, float s) {
    float f0 = __uint_as_float(p << 16) * s;
    float f1 = __uint_as_float(p & 0xFFFF0000u) * s;
    return pack2(f0, f1);
}

__device__ __forceinline__ float bf2f(ushort h) {
    return __uint_as_float((unsigned)h << 16);
}

// Decode one packed word (8 fp4 along k) -> 4 u32 of scaled bf16 pairs, sigma order.
__device__ __forceinline__ void dq_word(unsigned w, float s, unsigned o[4]) {
    unsigned lo  = w & 0x0F0F0F0Fu;
    unsigned hi  = (w >> 4) & 0x0F0F0F0Fu;
    unsigned mlo = lo & 0x07070707u, mhi = hi & 0x07070707u;
    unsigned Hlo = __builtin_amdgcn_perm(0x40404040u, 0x3F3F3F00u, mlo);
    unsigned Hhi = __builtin_amdgcn_perm(0x40404040u, 0x3F3F3F00u, mhi);
    unsigned Llo = __builtin_amdgcn_perm(0xC0804000u, 0xC0800000u, mlo);
    unsigned Lhi = __builtin_amdgcn_perm(0xC0804000u, 0xC0800000u, mhi);
    Hlo |= (lo & 0x08080808u) << 4;
    Hhi |= (hi & 0x08080808u) << 4;
    unsigned e01 = __builtin_amdgcn_perm(Hlo, Llo, 0x05010400u);
    unsigned e23 = __builtin_amdgcn_perm(Hlo, Llo, 0x07030602u);
    unsigned o01 = __builtin_amdgcn_perm(Hhi, Lhi, 0x05010400u);
    unsigned o23 = __builtin_amdgcn_perm(Hhi, Lhi, 0x07030602u);
    o[0] = scale2(e01, s); o[1] = scale2(e23, s);
    o[2] = scale2(o01, s); o[3] = scale2(o23, s);
}

__device__ __forceinline__ void gld16(const void* g, void* l) {
    __builtin_amdgcn_global_load_lds(
        (const __attribute__((address_space(1))) unsigned*)g,
        (__attribute__((address_space(3))) unsigned*)l, 16, 0, 0);
}

// prep (x fp32 -> sigma-permuted bf16) for all blocks; block 0 also does routing
__global__ __launch_bounds__(256) void k_prep_route(
        const float* __restrict__ x, ushort* __restrict__ xb,
        const int* __restrict__ eids, const float* __restrict__ probs,
        int* __restrict__ gcnt, int* __restrict__ gbase,
        int* __restrict__ tok, int* __restrict__ inv) {
    int tid = threadIdx.x;
    int idx = blockIdx.x * 256 + tid;
    const float4* p = (const float4*)(x + (size_t)idx * 8);
    float4 f0 = p[0], f1 = p[1];
    unsigned u0 = pack2(f0.x, f0.z);
    unsigned u1 = pack2(f1.x, f1.z);
    unsigned u2 = pack2(f0.y, f0.w);
    unsigned u3 = pack2(f1.y, f1.w);
    *(int4*)(xb + (size_t)idx * 8) = make_int4(u0, u1, u2, u3);

    if (blockIdx.x == 0) {
        __shared__ int lcnt[NE], lbase[NE], lcur[NE];
        if (tid < NE) lcnt[tid] = 0;
        __syncthreads();
        for (int i = tid; i < NSLOT; i += 256)
            atomicAdd(&lcnt[eids[i]], 1);
        __syncthreads();
        if (tid == 0) {
            int acc = 0;
            for (int e = 0; e < NE; e++) { lbase[e] = acc; acc += lcnt[e]; }
        }
        __syncthreads();
        if (tid < NE) lcur[tid] = lbase[tid];
        __syncthreads();
        for (int i = tid; i < NSLOT; i += 256) {
            int e = eids[i];
            int pos = atomicAdd(&lcur[e], 1);
            tok[pos] = i >> 1;
            inv[i] = pos;
        }
        for (int t = tid; t < T_TOK; t += 256)
            tok[NSLOT + t] = t;
        if (tid < NE) { gcnt[tid] = lcnt[tid]; gbase[tid] = lbase[tid]; }
        if (tid == 0) { gcnt[NE] = T_TOK; gbase[NE] = NSLOT; }
    }
}

// Dequant both weight sets to bf16 B^T (k sigma-permuted). z 0..8 = gate_up, 9..17 = down.
__global__ __launch_bounds__(256) void k_dq2(
        const int* __restrict__ gup, const float* __restrict__ gus,
        const int* __restrict__ sup, const float* __restrict__ sus,
        const int* __restrict__ dwp, const float* __restrict__ dsc,
        const int* __restrict__ sdp, const float* __restrict__ sds,
        ushort* __restrict__ wgu_t, ushort* __restrict__ wd_t) {
    int z = blockIdx.z;
    const int* wp; const float* sc; ushort* op; int KW;
    const int N = 2048;
    if (z < 9) {
        KW = 256;
        if (z < NE) { wp = gup + (size_t)z * KW * N; sc = gus + (size_t)z * (KW / 8) * N; }
        else        { wp = sup; sc = sus; }
        op = wgu_t + (size_t)z * KW * 8 * N;
    } else {
        KW = 128;
        int e = z - 9;
        if (blockIdx.x >= 16) return;
        if (e < NE) { wp = dwp + (size_t)e * KW * N; sc = dsc + (size_t)e * (KW / 8) * N; }
        else        { wp = sdp; sc = sds; }
        op = wd_t + (size_t)e * KW * 8 * N;
    }
    int kwt = blockIdx.x * 8 + threadIdx.x;
    int n   = blockIdx.y * 32 + threadIdx.y;
    unsigned w = (unsigned)wp[(size_t)kwt * N + n];
    float s = sc[(size_t)(kwt >> 3) * N + n];
    unsigned o[4]; dq_word(w, s, o);
    *(int4*)(op + (size_t)n * (KW * 8) + kwt * 8) = make_int4(o[0], o[1], o[2], o[3]);
}

// ---- GEMM 1: act[p,n] = silu(x@Wg)*(x@Wu). 128 rows x (64 gate + 64 up) per block.
__global__ __launch_bounds__(256) void k_gemm_gateup(
        const ushort* __restrict__ xb, const ushort* __restrict__ wgu_t,
        const int* __restrict__ gcnt, const int* __restrict__ gbase,
        const int* __restrict__ tokid, ushort* __restrict__ act) {
    int e = blockIdx.z, cnt = gcnt[e], m0 = blockIdx.y * 128;
    if (m0 >= cnt) return;
    int n0 = blockIdx.x * 64;
    int base = gbase[e];
    const ushort* wt = wgu_t + (size_t)e * 2048 * K_DIM;

    __shared__ __align__(16) ushort xs[128 * 64];
    __shared__ __align__(16) ushort bs[128 * 64];
    __shared__ int ltok[128];

    int tid = threadIdx.x;
    int lane = tid & 63, wv = tid >> 6;
    int lid = lane & 15, quad = lane >> 4;
    int wr = wv >> 1, wc = wv & 1;
    int l8 = lane >> 3, l7 = lane & 7;
    int chunk = (l7 ^ l8) * 8;

    if (tid < 128) ltok[tid] = (m0 + tid < cnt) ? tokid[base + m0 + tid] : 0;
    __syncthreads();

    const ushort* aSrc[4]; const ushort* bSrc[4];
    #pragma unroll
    for (int it = 0; it < 4; it++) {
        int rA = wv * 32 + it * 8 + l8;
        aSrc[it] = xb + (size_t)ltok[rA] * K_DIM + chunk;
        int h = rA >> 6, j = rA & 63;
        int col = (j < 32) ? (n0 + h * 32 + j) : (I_DIM + n0 + h * 32 + (j - 32));
        bSrc[it] = wt + (size_t)col * K_DIM + chunk;
    }

    f32x4 acc[4][4] = {};

    for (int k0 = 0; k0 < K_DIM; k0 += 64) {
        #pragma unroll
        for (int it = 0; it < 4; it++) {
            gld16(aSrc[it] + k0, &xs[(wv * 4 + it) * 512]);
            gld16(bSrc[it] + k0, &bs[(wv * 4 + it) * 512]);
        }
        __syncthreads();
        #pragma unroll
        for (int ks = 0; ks < 2; ks++) {
            int slot = ((ks * 4 + quad) ^ l7) * 8;
            short8 a[4], b[4];
            #pragma unroll
            for (int mt = 0; mt < 4; mt++)
                a[mt] = *(const short8*)&xs[(wr * 64 + mt * 16 + lid) * 64 + slot];
            #pragma unroll
            for (int nt = 0; nt < 4; nt++)
                b[nt] = *(const short8*)&bs[(wc * 64 + nt * 16 + lid) * 64 + slot];
            #pragma unroll
            for (int mt = 0; mt < 4; mt++)
                #pragma unroll
                for (int nt = 0; nt < 4; nt++)
                    acc[mt][nt] = __builtin_amdgcn_mfma_f32_16x16x32_bf16(
                        a[mt], b[nt], acc[mt][nt], 0, 0, 0);
        }
        __syncthreads();
    }

    int c7 = lid & 7;
    int delta = ((c7 >> 1) + ((c7 & 1) << 2)) - c7;   // sigma^-1 on stored I index
    #pragma unroll
    for (int mt = 0; mt < 4; mt++) {
        #pragma unroll
        for (int i = 0; i < 4; i++) {
            int row = wr * 64 + mt * 16 + quad * 4 + i;
            if (m0 + row < cnt) {
                size_t p = (size_t)(base + m0 + row);
                #pragma unroll
                for (int nt = 0; nt < 2; nt++) {
                    float g = acc[mt][nt][i], u = acc[mt][nt + 2][i];
                    float vv = g / (1.f + __expf(-g)) * u;
                    int ncol = n0 + wc * 32 + nt * 16 + lid;
                    __hip_bfloat16 hb = __float2bfloat16(vv);
                    act[p * I_DIM + ncol + delta] = *reinterpret_cast<ushort*>(&hb);
                }
            }
        }
    }
}

// ---- GEMM 2: y[p,n] = (act @ Wd)[p,n] (bf16, plain stores; combine applies probs)
__global__ __launch_bounds__(256) void k_gemm_down(
        const ushort* __restrict__ actb, const ushort* __restrict__ wd_t,
        const int* __restrict__ gcnt, const int* __restrict__ gbase,
        ushort* __restrict__ y) {
    int e = blockIdx.z, cnt = gcnt[e], m0 = blockIdx.y * 128;
    if (m0 >= cnt) return;
    int n0 = blockIdx.x * 128;
    int base = gbase[e];
    const ushort* wt = wd_t + (size_t)e * 2048 * I_DIM;

    __shared__ __align__(16) ushort xs[128 * 64];
    __shared__ __align__(16) ushort bs[128 * 64];

    int tid = threadIdx.x;
    int lane = tid & 63, wv = tid >> 6;
    int lid = lane & 15, quad = lane >> 4;
    int wr = wv >> 1, wc = wv & 1;
    int l8 = lane >> 3, l7 = lane & 7;
    int chunk = (l7 ^ l8) * 8;

    const ushort* aSrc[4]; const ushort* bSrc[4];
    #pragma unroll
    for (int it = 0; it < 4; it++) {
        int rA = wv * 32 + it * 8 + l8;
        int rr = m0 + rA; if (rr >= cnt) rr = cnt - 1;
        aSrc[it] = actb + (size_t)(base + rr) * I_DIM + chunk;
        bSrc[it] = wt + (size_t)(n0 + rA) * I_DIM + chunk;
    }

    f32x4 acc[4][4] = {};

    for (int i0 = 0; i0 < I_DIM; i0 += 64) {
        #pragma unroll
        for (int it = 0; it < 4; it++) {
            gld16(aSrc[it] + i0, &xs[(wv * 4 + it) * 512]);
            gld16(bSrc[it] + i0, &bs[(wv * 4 + it) * 512]);
        }
        __syncthreads();
        #pragma unroll
        for (int ks = 0; ks < 2; ks++) {
            int slot = ((ks * 4 + quad) ^ l7) * 8;
            short8 a[4], b[4];
            #pragma unroll
            for (int mt = 0; mt < 4; mt++)
                a[mt] = *(const short8*)&xs[(wr * 64 + mt * 16 + lid) * 64 + slot];
            #pragma unroll
            for (int nt = 0; nt < 4; nt++)
                b[nt] = *(const short8*)&bs[(wc * 64 + nt * 16 + lid) * 64 + slot];
            #pragma unroll
            for (int mt = 0; mt < 4; mt++)
                #pragma unroll
                for (int nt = 0; nt < 4; nt++)
                    acc[mt][nt] = __builtin_amdgcn_mfma_f32_16x16x32_bf16(
                        a[mt], b[nt], acc[mt][nt], 0, 0, 0);
        }
        __syncthreads();
    }

    #pragma unroll
    for (int mt = 0; mt < 4; mt++) {
        #pragma unroll
        for (int i = 0; i < 4; i++) {
            int row = wr * 64 + mt * 16 + quad * 4 + i;
            if (m0 + row < cnt) {
                ushort* yrow = y + (size_t)(base + m0 + row) * 2048 + n0 + wc * 64 + lid;
                #pragma unroll
                for (int nt = 0; nt < 4; nt++) {
                    __hip_bfloat16 hb = __float2bfloat16(acc[mt][nt][i]);
                    yrow[nt * 16] = *reinterpret_cast<ushort*>(&hb);
                }
            }
        }
    }
}

// out[t] = p0*y[inv[2t]] + p1*y[inv[2t+1]] + y[NSLOT+t]
__global__ __launch_bounds__(256) void k_combine(
        const ushort* __restrict__ y, const int* __restrict__ inv,
        const float* __restrict__ prb, float* __restrict__ out) {
    int idx = blockIdx.x * 256 + threadIdx.x;
    int t = idx >> 8;                 // 256 chunks of 8 cols per row
    int c = (idx & 255) * 8;
    int p0 = inv[2 * t], p1 = inv[2 * t + 1];
    float w0 = prb[2 * t], w1 = prb[2 * t + 1];
    int4 a = *(const int4*)(y + (size_t)p0 * 2048 + c);
    int4 b = *(const int4*)(y + (size_t)p1 * 2048 + c);
    int4 s = *(const int4*)(y + (size_t)(NSLOT + t) * 2048 + c);
    const ushort* au = (const ushort*)&a;
    const ushort* bu = (const ushort*)&b;
    const ushort* su = (const ushort*)&s;
    float o[8];
    #pragma unroll
    for (int j = 0; j < 8; j++)
        o[j] = w0 * bf2f(au[j]) + w1 * bf2f(bu[j]) + bf2f(su[j]);
    *(float4*)(out + (size_t)t * 2048 + c)     = *(float4*)&o[0];
    *(float4*)(out + (size_t)t * 2048 + c + 4) = *(float4*)&o[4];
}

extern "C" void kernel_launch(void* const* d_in, const int* in_sizes, int n_in,
                              void* d_out, int out_size, void* d_ws, size_t ws_size,
                              hipStream_t stream) {
    const float* x    = (const float*)d_in[0];
    const int*   gup  = (const int*)d_in[1];
    const float* gus  = (const float*)d_in[2];
    const int*   dwp  = (const int*)d_in[3];
    const float* dsc  = (const float*)d_in[4];
    const int*   sup  = (const int*)d_in[5];
    const float* sus  = (const float*)d_in[6];
    const int*   sdp  = (const int*)d_in[7];
    const float* sds  = (const float*)d_in[8];
    const int*   eids = (const int*)d_in[9];
    const float* prb  = (const float*)d_in[10];
    float* out = (float*)d_out;

    char*   ws    = (char*)d_ws;
    int*    gcnt  = (int*)(ws + 0);
    int*    gbase = (int*)(ws + 64);
    int*    tok   = (int*)(ws + 128);
    int*    inv   = (int*)(ws + 24704);
    ushort* xb    = (ushort*)(ws + WS_XB);
    ushort* act   = (ushort*)(ws + WS_ACT);
    ushort* y     = (ushort*)(ws + WS_Y);
    ushort* wgu_t = (ushort*)(ws + WS_WGU);
    ushort* wd_t  = (ushort*)(ws + WS_WD);

    k_prep_route<<<(T_TOK * K_DIM / 8) / 256, 256, 0, stream>>>(
        x, xb, eids, prb, gcnt, gbase, tok, inv);
    k_dq2<<<dim3(32, 64, 18), dim3(8, 32), 0, stream>>>(
        gup, gus, sup, sus, dwp, dsc, sdp, sds, wgu_t, wd_t);
    k_gemm_gateup<<<dim3(I_DIM / 64, MAXTILE, NE + 1), 256, 0, stream>>>(
        xb, wgu_t, gcnt, gbase, tok, act);
    k_gemm_down<<<dim3(K_DIM / 128, MAXTILE, NE + 1), 256, 0, stream>>>(
        act, wd_t, gcnt, gbase, y);
    k_combine<<<(T_TOK * K_DIM / 8) / 256, 256, 0, stream>>>(y, inv, prb, out);
}